// Round 5
// baseline (379.917 us; speedup 1.0000x reference)
//
#include <hip/hip_runtime.h>
#include <hip/hip_bf16.h>
#include <math.h>

// Problem constants (from reference): B=8, S=4096, D=2048, E=64, TOP_K=2
#define BB 8
#define SS 4096
#define DD 2048
#define EE 64
#define NCHUNK 128                     // S split into 128 chunks
#define ROWS (SS / NCHUNK)             // 32 rows per chunk
#define NSLICE (NCHUNK * 2)            // 256 logit-partial slices per batch

// Native clang vector so __builtin_nontemporal_load accepts it
// (HIP_vector_type float4 is a struct and is rejected).
typedef float f32x4 __attribute__((ext_vector_type(4)));

// Kernel 1 (fused): stream x (nontemporal), accumulate column sums for a
// (b, S-chunk, half-D) tile, then dot against the matching W half-slice to
// emit 64 partial logits. blk = b*256 + c*2 + h.
// grid = 2048 blocks at 4 resident blocks/CU -> TWO generations per CU:
// gen-1's phase-B (L2-hot W dot) overlaps gen-2's phase-A HBM streaming,
// hiding the dot tail that was exposed with a one-generation grid.
__global__ void __launch_bounds__(256, 4)
fused_stream_kernel(const float* __restrict__ x,
                    const float* __restrict__ W,
                    float* __restrict__ plogit) {
    __shared__ float xs[DD / 2];     // 4 KB: this block's column sums
    __shared__ float lred[4][EE];    // 1 KB: quarter partial dots

    int blk = blockIdx.x;
    int h   = blk & 1;                    // which half of D
    int c   = (blk >> 1) & (NCHUNK - 1);
    int b   = blk >> 8;                   // 2048/256 = 8 batches
    int tid = threadIdx.x;
    int d   = h * (DD / 2) + tid * 4;

    // Phase A: column sums over ROWS rows (4 independent accumulators,
    // nontemporal 16B/lane coalesced loads — x is read-once, keep W in L2).
    const f32x4* xp = (const f32x4*)(x + (size_t)b * SS * DD
                                       + (size_t)c * ROWS * DD + d);
    f32x4 a0 = (f32x4)(0.f);
    f32x4 a1 = (f32x4)(0.f);
    f32x4 a2 = (f32x4)(0.f);
    f32x4 a3 = (f32x4)(0.f);
    const size_t rs = DD / 4;             // f32x4 row stride
    #pragma unroll 4
    for (int r = 0; r < ROWS; r += 4) {
        f32x4 v0 = __builtin_nontemporal_load(&xp[(size_t)(r + 0) * rs]);
        f32x4 v1 = __builtin_nontemporal_load(&xp[(size_t)(r + 1) * rs]);
        f32x4 v2 = __builtin_nontemporal_load(&xp[(size_t)(r + 2) * rs]);
        f32x4 v3 = __builtin_nontemporal_load(&xp[(size_t)(r + 3) * rs]);
        a0 += v0;
        a1 += v1;
        a2 += v2;
        a3 += v3;
    }
    f32x4 acc = (a0 + a1) + (a2 + a3);
    ((f32x4*)xs)[tid] = acc;
    __syncthreads();

    // Phase B: partial logits for this d-span. thread -> (expert e, quarter q)
    int e = tid & 63;
    int q = tid >> 6;
    const int QF4 = (DD / 2 / 4) / 4;     // 64 f32x4s per quarter-span
    const f32x4* wp = (const f32x4*)(W + (size_t)e * DD
                                       + h * (DD / 2) + q * (QF4 * 4));
    const f32x4* xq = (const f32x4*)(xs + q * (QF4 * 4));
    float dot = 0.f;
    #pragma unroll 8
    for (int i = 0; i < QF4; ++i) {
        f32x4 wv = wp[i];
        f32x4 xv = xq[i];
        f32x4 p  = wv * xv;
        dot += (p.x + p.y) + (p.z + p.w);
    }
    lred[q][e] = dot;
    __syncthreads();

    if (tid < EE) {
        plogit[(size_t)blk * EE + tid] =
            lred[0][tid] + lred[1][tid] + lred[2][tid] + lred[3][tid];
    }
}

// Kernel 2: per-batch reduce the 256 logit-partial slices, scale by 1/S,
// add bias, top-2 + softmax. grid = 8 blocks, 256 threads.
__global__ void gate_kernel(const float* __restrict__ plogit,
                            const float* __restrict__ bias,
                            float* __restrict__ out) {
    __shared__ float lred[4][EE];
    __shared__ float logits[EE];

    int b   = blockIdx.x;
    int tid = threadIdx.x;
    int e   = tid & 63;
    int g   = tid >> 6;                   // group of NSLICE/4 slices

    float s = 0.f;
    #pragma unroll 8
    for (int j = g * (NSLICE / 4); j < (g + 1) * (NSLICE / 4); ++j)
        s += plogit[((size_t)b * NSLICE + j) * EE + e];
    lred[g][e] = s;
    __syncthreads();

    if (tid < EE) {
        logits[tid] = (lred[0][tid] + lred[1][tid] + lred[2][tid] + lred[3][tid])
                      * (1.0f / SS) + bias[tid];
    }
    __syncthreads();

    // top-2 (stable: lowest index wins ties, matching lax.top_k) + softmax
    if (tid == 0) {
        float m1 = -INFINITY, m2 = -INFINITY;
        int i1 = 0, i2 = 0;
        for (int i = 0; i < EE; ++i) {
            float v = logits[i];
            if (v > m1) { m2 = m1; i2 = i1; m1 = v; i1 = i; }
            else if (v > m2) { m2 = v; i2 = i; }
        }
        float e2 = expf(m2 - m1);
        float inv = 1.0f / (1.0f + e2);
        // outputs concatenated flat: weights [8,2] then indices [8,2]
        out[b * 2 + 0] = inv;
        out[b * 2 + 1] = e2 * inv;
        out[2 * BB + b * 2 + 0] = (float)i1;
        out[2 * BB + b * 2 + 1] = (float)i2;
    }
}

extern "C" void kernel_launch(void* const* d_in, const int* in_sizes, int n_in,
                              void* d_out, int out_size, void* d_ws, size_t ws_size,
                              hipStream_t stream) {
    const float* x  = (const float*)d_in[0];   // [8, 4096, 2048]
    const float* W  = (const float*)d_in[1];   // [64, 2048]
    const float* bb = (const float*)d_in[2];   // [64]
    float* out      = (float*)d_out;           // 32 floats: weights(16) + indices(16)
    float* plogit   = (float*)d_ws;            // 2048*64 floats = 512 KB

    fused_stream_kernel<<<BB * NCHUNK * 2, 256, 0, stream>>>(x, W, plogit);
    gate_kernel<<<BB, 256, 0, stream>>>(plogit, bb, out);
}